// Round 1
// baseline (202.934 us; speedup 1.0000x reference)
//
#include <hip/hip_runtime.h>

namespace {

constexpr int QN = 9;
constexpr int YD = 2048;
constexpr int XD = 2048;

constexpr float PRc     = 0.71f;
constexpr float ALPHA1c = 1.35f;
constexpr float MUYc    = 0.01f;
constexpr float ICVc    = 1.4f - 1.0f;   // VUY - 1 = 0.4

__global__ __launch_bounds__(256) void lb_fused(
    const float* __restrict__ Fin,
    const float* __restrict__ Gin,
    const float* __restrict__ Feqin,
    float* __restrict__ out)
{
    constexpr int EXI[QN] = {1, 0, -1, 0, 1, -1, -1, 1, 0};
    constexpr int EYI[QN] = {0, 1, 0, -1, 1, 1, -1, -1, 0};

    const int tid = blockIdx.x * 256 + threadIdx.x;
    const int x0  = (tid & (XD / 4 - 1)) * 4;
    const int y   = tid >> 9;                 // XD/4 = 512 groups per row
    const size_t plane = (size_t)YD * XD;
    const size_t base  = (size_t)y * XD + x0;

    float f[QN][4];
    float feq[QN][4];
    float sumG[4] = {0.f, 0.f, 0.f, 0.f};

    #pragma unroll
    for (int q = 0; q < QN; ++q) {
        const float4 fv = *reinterpret_cast<const float4*>(Fin   + q * plane + base);
        const float4 fe = *reinterpret_cast<const float4*>(Feqin + q * plane + base);
        const float4 gv = *reinterpret_cast<const float4*>(Gin   + q * plane + base);
        f[q][0] = fv.x; f[q][1] = fv.y; f[q][2] = fv.z; f[q][3] = fv.w;
        feq[q][0] = fe.x; feq[q][1] = fe.y; feq[q][2] = fe.z; feq[q][3] = fe.w;
        sumG[0] += gv.x; sumG[1] += gv.y; sumG[2] += gv.z; sumG[3] += gv.w;
    }

    float rho[4], ux[4], uy[4], E[4], T[4], qx[4], qy[4], omgT[4], omg[4];
    float wA[4], wB[4], wC[4];

    #pragma unroll
    for (int j = 0; j < 4; ++j) {
        float s = 0.f;
        #pragma unroll
        for (int q = 0; q < QN; ++q) s += f[q][j];
        const float r  = fmaxf(s, 1e-6f);
        const float ir = 1.0f / r;
        const float vx = (f[0][j] - f[2][j] + f[4][j] - f[5][j] - f[6][j] + f[7][j]) * ir;
        const float vy = (f[1][j] - f[3][j] + f[4][j] + f[5][j] - f[6][j] - f[7][j]) * ir;
        const float e  = sumG[j] * 0.5f * ir;
        const float uu = vx * vx + vy * vy;
        const float t  = fmaxf(ICVc * (e - 0.5f * uu), 1e-6f);
        const float rhoH2 = 2.0f * r * (e + t);
        const float one_mt = 1.0f - t;

        float eps = 0.f;
        #pragma unroll
        for (int q = 0; q < QN; ++q)
            eps += fabsf(f[q][j] - feq[q][j]) / (feq[q][j] + 1e-10f);
        eps *= (1.0f / 9.0f);

        const float tau_DL = MUYc / (r * t) + 0.5f;
        const float alpha  = (eps < 1.0f) ? ALPHA1c : (1.0f / tau_DL);
        const float tau    = alpha * tau_DL;
        const float tauT   = 0.5f + (tau - 0.5f) / PRc;

        omg[j]  = 1.0f / tau;
        omgT[j] = 1.0f / tauT;
        rho[j] = r; ux[j] = vx; uy[j] = vy; E[j] = e; T[j] = t;
        qx[j] = rhoH2 * vx; qy[j] = rhoH2 * vy;
        wA[j] = one_mt * t * 0.5f;     // planes 9..12
        wB[j] = t * t * 0.25f;         // planes 13..16
        wC[j] = one_mt * one_mt;       // plane 17
    }

    // ---- BGK collision + scatter-streaming: out[q][(y-ey)&2047][(x+ex)&2047] ----
    #pragma unroll
    for (int q = 0; q < QN; ++q) {
        const int yp = (y - EYI[q]) & (YD - 1);
        float fp[4];
        #pragma unroll
        for (int j = 0; j < 4; ++j)
            fp[j] = f[q][j] - omg[j] * (f[q][j] - feq[q][j]);
        float* oplane = out + q * plane + (size_t)yp * XD;
        if (EXI[q] == 0) {
            *reinterpret_cast<float4*>(oplane + x0) =
                make_float4(fp[0], fp[1], fp[2], fp[3]);
        } else {
            #pragma unroll
            for (int j = 0; j < 4; ++j) {
                const int xp = (x0 + j + EXI[q]) & (XD - 1);
                oplane[xp] = fp[j];
            }
        }
    }

    // ---- aligned float4 stores for w and moment fields ----
    auto store4 = [&](int p, const float* v) {
        *reinterpret_cast<float4*>(out + (size_t)p * plane + base) =
            make_float4(v[0], v[1], v[2], v[3]);
    };
    store4(9, wA);  store4(10, wA); store4(11, wA); store4(12, wA);
    store4(13, wB); store4(14, wB); store4(15, wB); store4(16, wB);
    store4(17, wC);
    store4(18, rho); store4(19, ux); store4(20, uy); store4(21, E);
    store4(22, T);   store4(23, qx); store4(24, qy); store4(25, omgT);
}

} // namespace

extern "C" void kernel_launch(void* const* d_in, const int* in_sizes, int n_in,
                              void* d_out, int out_size, void* d_ws, size_t ws_size,
                              hipStream_t stream) {
    const float* F   = (const float*)d_in[0];
    const float* G   = (const float*)d_in[1];
    const float* Feq = (const float*)d_in[2];
    float* out = (float*)d_out;

    const int total_threads = (XD / 4) * YD;   // 1,048,576
    const int block = 256;
    const int grid  = total_threads / block;   // 4096
    lb_fused<<<grid, block, 0, stream>>>(F, G, Feq, out);
}

// Round 2
// 193.124 us; speedup vs baseline: 1.0508x; 1.0508x over previous
//
#include <hip/hip_runtime.h>

namespace {

constexpr int QN = 9;
constexpr int YD = 2048;
constexpr int XD = 2048;

constexpr float PRc     = 0.71f;
constexpr float ALPHA1c = 1.35f;
constexpr float MUYc    = 0.01f;
constexpr float ICVc    = 1.4f - 1.0f;   // VUY - 1 = 0.4

__global__ __launch_bounds__(256) void lb_fused(
    const float* __restrict__ Fin,
    const float* __restrict__ Gin,
    const float* __restrict__ Feqin,
    float* __restrict__ out)
{
    constexpr int EXI[QN] = {1, 0, -1, 0, 1, -1, -1, 1, 0};
    constexpr int EYI[QN] = {0, 1, 0, -1, 1, 1, -1, -1, 0};

    const int tid = blockIdx.x * 256 + threadIdx.x;
    const int x0  = (tid & (XD / 2 - 1)) * 2;
    const int y   = tid >> 10;                // XD/2 = 1024 groups per row
    const size_t plane = (size_t)YD * XD;
    const size_t base  = (size_t)y * XD + x0;

    float f[QN][2];
    float feq[QN][2];
    float sumG[2] = {0.f, 0.f};

    #pragma unroll
    for (int q = 0; q < QN; ++q) {
        const float2 fv = *reinterpret_cast<const float2*>(Fin   + q * plane + base);
        const float2 fe = *reinterpret_cast<const float2*>(Feqin + q * plane + base);
        const float2 gv = *reinterpret_cast<const float2*>(Gin   + q * plane + base);
        f[q][0] = fv.x;   f[q][1] = fv.y;
        feq[q][0] = fe.x; feq[q][1] = fe.y;
        sumG[0] += gv.x;  sumG[1] += gv.y;
    }

    float rho[2], ux[2], uy[2], E[2], T[2], qx[2], qy[2], omgT[2], omg[2];
    float wA[2], wB[2], wC[2];

    #pragma unroll
    for (int j = 0; j < 2; ++j) {
        float s = 0.f;
        #pragma unroll
        for (int q = 0; q < QN; ++q) s += f[q][j];
        const float r  = fmaxf(s, 1e-6f);
        const float ir = 1.0f / r;
        const float vx = (f[0][j] - f[2][j] + f[4][j] - f[5][j] - f[6][j] + f[7][j]) * ir;
        const float vy = (f[1][j] - f[3][j] + f[4][j] + f[5][j] - f[6][j] - f[7][j]) * ir;
        const float e  = sumG[j] * 0.5f * ir;
        const float uu = vx * vx + vy * vy;
        const float t  = fmaxf(ICVc * (e - 0.5f * uu), 1e-6f);
        const float rhoH2 = 2.0f * r * (e + t);
        const float one_mt = 1.0f - t;

        float eps = 0.f;
        #pragma unroll
        for (int q = 0; q < QN; ++q)
            eps += fabsf(f[q][j] - feq[q][j]) / (feq[q][j] + 1e-10f);
        eps *= (1.0f / 9.0f);

        const float tau_DL = MUYc / (r * t) + 0.5f;
        const float alpha  = (eps < 1.0f) ? ALPHA1c : (1.0f / tau_DL);
        const float tau    = alpha * tau_DL;
        const float tauT   = 0.5f + (tau - 0.5f) / PRc;

        omg[j]  = 1.0f / tau;
        omgT[j] = 1.0f / tauT;
        rho[j] = r; ux[j] = vx; uy[j] = vy; E[j] = e; T[j] = t;
        qx[j] = rhoH2 * vx; qy[j] = rhoH2 * vy;
        wA[j] = one_mt * t * 0.5f;     // planes 9..12
        wB[j] = t * t * 0.25f;         // planes 13..16
        wC[j] = one_mt * one_mt;       // plane 17
    }

    // ---- BGK collision + scatter-streaming: out[q][(y-ey)&2047][(x+ex)&2047] ----
    #pragma unroll
    for (int q = 0; q < QN; ++q) {
        const int yp = (y - EYI[q]) & (YD - 1);
        float fp[2];
        #pragma unroll
        for (int j = 0; j < 2; ++j)
            fp[j] = f[q][j] - omg[j] * (f[q][j] - feq[q][j]);
        float* oplane = out + q * plane + (size_t)yp * XD;
        if (EXI[q] == 0) {
            *reinterpret_cast<float2*>(oplane + x0) = make_float2(fp[0], fp[1]);
        } else {
            #pragma unroll
            for (int j = 0; j < 2; ++j) {
                const int xp = (x0 + j + EXI[q]) & (XD - 1);
                oplane[xp] = fp[j];
            }
        }
    }

    // ---- aligned float2 stores for w and moment fields ----
    auto store2 = [&](int p, const float* v) {
        *reinterpret_cast<float2*>(out + (size_t)p * plane + base) =
            make_float2(v[0], v[1]);
    };
    store2(9, wA);  store2(10, wA); store2(11, wA); store2(12, wA);
    store2(13, wB); store2(14, wB); store2(15, wB); store2(16, wB);
    store2(17, wC);
    store2(18, rho); store2(19, ux); store2(20, uy); store2(21, E);
    store2(22, T);   store2(23, qx); store2(24, qy); store2(25, omgT);
}

} // namespace

extern "C" void kernel_launch(void* const* d_in, const int* in_sizes, int n_in,
                              void* d_out, int out_size, void* d_ws, size_t ws_size,
                              hipStream_t stream) {
    const float* F   = (const float*)d_in[0];
    const float* G   = (const float*)d_in[1];
    const float* Feq = (const float*)d_in[2];
    float* out = (float*)d_out;

    const int total_threads = (XD / 2) * YD;   // 2,097,152
    const int block = 256;
    const int grid  = total_threads / block;   // 8192
    lb_fused<<<grid, block, 0, stream>>>(F, G, Feq, out);
}

// Round 3
// 184.995 us; speedup vs baseline: 1.0970x; 1.0439x over previous
//
#include <hip/hip_runtime.h>

namespace {

constexpr int QN = 9;
constexpr int YD = 2048;
constexpr int XD = 2048;

constexpr float PRc     = 0.71f;
constexpr float ALPHA1c = 1.35f;
constexpr float MUYc    = 0.01f;
constexpr float ICVc    = 1.4f - 1.0f;   // VUY - 1 = 0.4

typedef float fvec2 __attribute__((ext_vector_type(2)));

__global__ __launch_bounds__(256) void lb_fused(
    const float* __restrict__ Fin,
    const float* __restrict__ Gin,
    const float* __restrict__ Feqin,
    float* __restrict__ out)
{
    constexpr int EXI[QN] = {1, 0, -1, 0, 1, -1, -1, 1, 0};
    constexpr int EYI[QN] = {0, 1, 0, -1, 1, 1, -1, -1, 0};

    const int tid  = blockIdx.x * 256 + threadIdx.x;
    const int lane = threadIdx.x & 63;
    const int x0   = (tid & (XD / 2 - 1)) * 2;
    const int y    = tid >> 10;               // XD/2 = 1024 pairs per row
    const size_t plane = (size_t)YD * XD;
    const size_t base  = (size_t)y * XD + x0;

    float f[QN][2];
    float feq[QN][2];
    float sumG[2] = {0.f, 0.f};

    #pragma unroll
    for (int q = 0; q < QN; ++q) {
        const fvec2 fv = __builtin_nontemporal_load(
            reinterpret_cast<const fvec2*>(Fin   + q * plane + base));
        const fvec2 fe = __builtin_nontemporal_load(
            reinterpret_cast<const fvec2*>(Feqin + q * plane + base));
        const fvec2 gv = __builtin_nontemporal_load(
            reinterpret_cast<const fvec2*>(Gin   + q * plane + base));
        f[q][0] = fv.x;   f[q][1] = fv.y;
        feq[q][0] = fe.x; feq[q][1] = fe.y;
        sumG[0] += gv.x;  sumG[1] += gv.y;
    }

    float rho[2], ux[2], uy[2], E[2], T[2], qx[2], qy[2], omgT[2], omg[2];
    float wA[2], wB[2], wC[2];

    #pragma unroll
    for (int j = 0; j < 2; ++j) {
        float s = 0.f;
        #pragma unroll
        for (int q = 0; q < QN; ++q) s += f[q][j];
        const float r  = fmaxf(s, 1e-6f);
        const float ir = 1.0f / r;
        const float vx = (f[0][j] - f[2][j] + f[4][j] - f[5][j] - f[6][j] + f[7][j]) * ir;
        const float vy = (f[1][j] - f[3][j] + f[4][j] + f[5][j] - f[6][j] - f[7][j]) * ir;
        const float e  = sumG[j] * 0.5f * ir;
        const float uu = vx * vx + vy * vy;
        const float t  = fmaxf(ICVc * (e - 0.5f * uu), 1e-6f);
        const float rhoH2 = 2.0f * r * (e + t);
        const float one_mt = 1.0f - t;

        float eps = 0.f;
        #pragma unroll
        for (int q = 0; q < QN; ++q)
            eps += fabsf(f[q][j] - feq[q][j]) / (feq[q][j] + 1e-10f);
        eps *= (1.0f / 9.0f);

        const float tau_DL = MUYc / (r * t) + 0.5f;
        const float alpha  = (eps < 1.0f) ? ALPHA1c : (1.0f / tau_DL);
        const float tau    = alpha * tau_DL;
        const float tauT   = 0.5f + (tau - 0.5f) / PRc;

        omg[j]  = 1.0f / tau;
        omgT[j] = 1.0f / tauT;
        rho[j] = r; ux[j] = vx; uy[j] = vy; E[j] = e; T[j] = t;
        qx[j] = rhoH2 * vx; qy[j] = rhoH2 * vy;
        wA[j] = one_mt * t * 0.5f;     // planes 9..12
        wB[j] = t * t * 0.25f;         // planes 13..16
        wC[j] = one_mt * one_mt;       // plane 17
    }

    // ---- BGK collision + scatter-streaming: out[q][(y-ey)&2047][(x+ex)&2047] ----
    // For ex=±1 planes, build the shifted ALIGNED pair via shuffle:
    //   out[x+ex] = fp(x)  =>  aligned pair at (x0+1+ex) is (fp1_own, fp0_{lane+1}).
    #pragma unroll
    for (int q = 0; q < QN; ++q) {
        const int yp = (y - EYI[q]) & (YD - 1);
        float fp0 = f[q][0] - omg[0] * (f[q][0] - feq[q][0]);
        float fp1 = f[q][1] - omg[1] * (f[q][1] - feq[q][1]);
        float* oplane = out + q * plane + (size_t)yp * XD;
        const int ex = EXI[q];
        if (ex == 0) {
            fvec2 pv; pv.x = fp0; pv.y = fp1;
            __builtin_nontemporal_store(pv, reinterpret_cast<fvec2*>(oplane + x0));
        } else {
            const float nb = __shfl_down(fp0, 1);      // fp0 of lane+1
            fvec2 pv; pv.x = fp1; pv.y = nb;
            const int xp = (ex == 1) ? (x0 + 2) : x0;  // in-row, no wrap needed
            if (lane != 63)
                __builtin_nontemporal_store(pv, reinterpret_cast<fvec2*>(oplane + xp));
            if (lane == 0)
                oplane[(x0 + ex) & (XD - 1)] = fp0;
            if (lane == 63)
                oplane[(x0 + 1 + ex) & (XD - 1)] = fp1;
        }
    }

    // ---- aligned nontemporal pair stores for w and moment fields ----
    auto store2 = [&](int p, const float* v) {
        fvec2 pv; pv.x = v[0]; pv.y = v[1];
        __builtin_nontemporal_store(pv,
            reinterpret_cast<fvec2*>(out + (size_t)p * plane + base));
    };
    store2(9, wA);  store2(10, wA); store2(11, wA); store2(12, wA);
    store2(13, wB); store2(14, wB); store2(15, wB); store2(16, wB);
    store2(17, wC);
    store2(18, rho); store2(19, ux); store2(20, uy); store2(21, E);
    store2(22, T);   store2(23, qx); store2(24, qy); store2(25, omgT);
}

} // namespace

extern "C" void kernel_launch(void* const* d_in, const int* in_sizes, int n_in,
                              void* d_out, int out_size, void* d_ws, size_t ws_size,
                              hipStream_t stream) {
    const float* F   = (const float*)d_in[0];
    const float* G   = (const float*)d_in[1];
    const float* Feq = (const float*)d_in[2];
    float* out = (float*)d_out;

    const int total_threads = (XD / 2) * YD;   // 2,097,152
    const int block = 256;
    const int grid  = total_threads / block;   // 8192
    lb_fused<<<grid, block, 0, stream>>>(F, G, Feq, out);
}